// Round 1
// 1064.525 us; speedup vs baseline: 1.4813x; 1.4813x over previous
//
#include <hip/hip_runtime.h>

#define K_DIM 4096
#define N_DIM 11008
#define M_DIM 8192
#define K2B (K_DIM * 2)  // bf16 row stride in bytes

// ---- old 128^2 kernel tile params (fallback path) ----
#define BM 128
#define BN 128
#define BK 32

typedef __bf16 bf16x8_t __attribute__((ext_vector_type(8)));
typedef float f32x4_t __attribute__((ext_vector_type(4)));

#define GLD_LDS16(g, l)                                                        \
  __builtin_amdgcn_global_load_lds(                                            \
      (const __attribute__((address_space(1))) void*)(g),                      \
      (__attribute__((address_space(3))) void*)(l), 16, 0, 0)

// ---------------------------------------------------------------------------
// Kernel 1: unpack int4 + dequant (s*q + b) -> bf16 W (N_DIM x K_DIM, K-contig)
// ---------------------------------------------------------------------------
__global__ void dequant_w(const int* __restrict__ wp, const float* __restrict__ sc,
                          const float* __restrict__ bg, __bf16* __restrict__ W) {
  const int tid = blockIdx.x * 256 + threadIdx.x;  // < 11008*512
  const unsigned w = (unsigned)wp[tid];
  const int row = tid >> 9;
  const int word = tid & 511;
  const int g = word >> 4;
  const float s = sc[row * 32 + g];
  const float b = bg[row * 32 + g];
  bf16x8_t v;
#pragma unroll
  for (int i = 0; i < 8; ++i)
    v[i] = (__bf16)(s * (float)((w >> (4 * i)) & 15u) + b);
  ((bf16x8_t*)W)[tid] = v;
}

// ---------------------------------------------------------------------------
// Kernel 2: x fp32 -> bf16 (8 elems/thread)
// ---------------------------------------------------------------------------
__global__ void cvt_x(const float* __restrict__ X, __bf16* __restrict__ Xb) {
  const size_t t = (size_t)blockIdx.x * 256 + threadIdx.x;
  const float4* s = ((const float4*)X) + 2 * t;
  const float4 f0 = s[0], f1 = s[1];
  bf16x8_t v;
  v[0] = (__bf16)f0.x; v[1] = (__bf16)f0.y; v[2] = (__bf16)f0.z; v[3] = (__bf16)f0.w;
  v[4] = (__bf16)f1.x; v[5] = (__bf16)f1.y; v[6] = (__bf16)f1.z; v[7] = (__bf16)f1.w;
  ((bf16x8_t*)Xb)[t] = v;
}

// ---------------------------------------------------------------------------
// Kernel 3: 256x256x64 8-phase bf16 GEMM-BT (m201 template, T1+T2+T3/T4+T5).
// C[M,N] = A[M,K] * W[N,K]^T + bias.  512 thr = 8 waves (2M x 4N), each wave
// 128x64 via 8x4 acc of 16x16x32 MFMA.  LDS 128KB: buf{0,1} x (A 32K | B 32K),
// tile kt -> buf[kt&1] (static: phases 1-4 read buf0, 5-8 buf1).
// XOR slot swizzle (slot ^= row&7, 16B slots) on gload source + ds_read addr.
// vmcnt(6) at phases 4/8 only (3 half-tiles in flight).
// ---------------------------------------------------------------------------
__device__ __forceinline__ void stage2(const char* g, char* l) {
  GLD_LDS16(g, l);
  GLD_LDS16(g + (size_t)64 * K2B, l + 8192);
}

template <int AM, int AN>
__device__ __forceinline__ void mfma_quad(f32x4_t (&acc)[8][4],
                                          const bf16x8_t (&A)[4][2],
                                          const bf16x8_t (&B)[2][2]) {
#pragma unroll
  for (int mi = 0; mi < 4; ++mi)
#pragma unroll
    for (int nj = 0; nj < 2; ++nj)
#pragma unroll
      for (int ks = 0; ks < 2; ++ks)
        acc[AM + mi][AN + nj] = __builtin_amdgcn_mfma_f32_16x16x32_bf16(
            A[mi][ks], B[nj][ks], acc[AM + mi][AN + nj], 0, 0, 0);
}

__device__ __forceinline__ void rd_a(bf16x8_t (&d)[4][2], const char* p, int s0, int s1) {
#pragma unroll
  for (int mi = 0; mi < 4; ++mi) {
    d[mi][0] = *(const bf16x8_t*)(p + mi * 2048 + s0);
    d[mi][1] = *(const bf16x8_t*)(p + mi * 2048 + s1);
  }
}
__device__ __forceinline__ void rd_b(bf16x8_t (&d)[2][2], const char* p, int s0, int s1) {
#pragma unroll
  for (int nj = 0; nj < 2; ++nj) {
    d[nj][0] = *(const bf16x8_t*)(p + nj * 2048 + s0);
    d[nj][1] = *(const bf16x8_t*)(p + nj * 2048 + s1);
  }
}

#define PH_SYNC_IN()                                                           \
  do {                                                                         \
    __builtin_amdgcn_s_barrier();                                              \
    asm volatile("s_waitcnt lgkmcnt(0)" ::: "memory");                         \
    __builtin_amdgcn_sched_barrier(0);                                         \
    __builtin_amdgcn_s_setprio(1);                                             \
  } while (0)
#define PH_SYNC_OUT()                                                          \
  do {                                                                         \
    __builtin_amdgcn_s_setprio(0);                                             \
    __builtin_amdgcn_sched_barrier(0);                                         \
    __builtin_amdgcn_s_barrier();                                              \
  } while (0)

__launch_bounds__(512, 2)
__global__ void qgemm8(const __bf16* __restrict__ Ab, const __bf16* __restrict__ Bw,
                       const float* __restrict__ bias, float* __restrict__ C) {
  __shared__ alignas(128) char smem[131072];
  const int tid = threadIdx.x;
  const int lane = tid & 63;
  const int wave = tid >> 6;
  const int wm = wave >> 2;  // 0..1
  const int wn = wave & 3;   // 0..3
  const int l16 = lane & 15;
  const int quad = lane >> 4;

  // T1: bijective XCD swizzle; nwg = 43*32 = 1376 = 8*172. m-major within an
  // XCD chunk (4 full M-rows of 43): pins 2MB A-panel in each XCD's L2.
  int bid = (int)blockIdx.x;
  bid = (bid & 7) * 172 + (bid >> 3);
  const int m0 = (bid / 43) * 256;
  const int n0 = (bid % 43) * 256;

  // staging source (per-lane, pre-swizzled: phys slot L&7 holds logical slot
  // (L&7)^(row&7); row&7 == (tid>>3)&7 for every staged octet)
  const int rr = tid >> 3;                          // 0..63
  const int sw = ((tid & 7) ^ (rr & 7)) * 16;
  const char* gA = (const char*)Ab + (size_t)(m0 + rr) * K2B + sw;
  const char* gB = (const char*)Bw + (size_t)(n0 + rr) * K2B + sw;
  // staging LDS dest (wave-uniform base; HW adds lane*16)
  char* lA = smem + wave * 1024;
  char* lB = smem + 32768 + wave * 1024;

  // fragment ds_read: logical slot s=ks*4+quad at phys byte ((s^(row&7))*16);
  // row&7 == l16&7 for all fragment rows -> conflict-free (8 lanes/bank-group)
  const int s0 = ((0 + quad) ^ (l16 & 7)) * 16;
  const int s1 = ((4 + quad) ^ (l16 & 7)) * 16;
  const char* fA = smem + (wm * 64 + l16) * 128;
  const char* fB = smem + 32768 + (wn * 32 + l16) * 128;

  f32x4_t acc[8][4];
#pragma unroll
  for (int i = 0; i < 8; ++i)
#pragma unroll
    for (int j = 0; j < 4; ++j) acc[i][j] = (f32x4_t){0.f, 0.f, 0.f, 0.f};

  // prologue: tile0 all 4 halves -> buf0, tile1 Ah0/Ah1/Bh0 -> buf1 (14 loads)
  stage2(gA, lA);
  stage2(gA + (size_t)128 * K2B, lA + 16384);
  stage2(gB, lB);
  stage2(gB + (size_t)128 * K2B, lB + 16384);
  stage2(gA + 128, lA + 65536);
  stage2(gA + (size_t)128 * K2B + 128, lA + 65536 + 16384);
  stage2(gB + 128, lB + 65536);
  asm volatile("s_waitcnt vmcnt(6)" ::: "memory");  // tile0 complete
  __builtin_amdgcn_s_barrier();

  bf16x8_t fa0[4][2], fa1[4][2], fb0[2][2], fb1[2][2];

#pragma unroll 1
  for (int it = 0; it < 32; ++it) {
    const size_t o1 = (size_t)(2 * it + 1) * 128;
    const int tt2 = 2 * it + 2, tt3 = 2 * it + 3;
    const size_t o2 = (size_t)(tt2 < 64 ? tt2 : 63) * 128;  // clamp: dead data
    const size_t o3 = (size_t)(tt3 < 64 ? tt3 : 63) * 128;

    // phi1: read buf0 fa0+fb0 (12 ds_read); stage B(t+1)h1 -> buf1
    rd_a(fa0, fA, s0, s1);
    rd_b(fb0, fB, s0, s1);
    stage2(gB + (size_t)128 * K2B + o1, lB + 65536 + 16384);
    PH_SYNC_IN();
    mfma_quad<0, 0>(acc, fa0, fb0);
    PH_SYNC_OUT();

    // phi2: read buf0 fa1; stage A(t+2)h0 -> buf0 (region dead since phi1)
    rd_a(fa1, fA + 16384, s0, s1);
    stage2(gA + o2, lA);
    PH_SYNC_IN();
    mfma_quad<4, 0>(acc, fa1, fb0);
    PH_SYNC_OUT();

    // phi3: read buf0 fb1; stage A(t+2)h1 -> buf0
    rd_b(fb1, fB + 16384, s0, s1);
    stage2(gA + (size_t)128 * K2B + o2, lA + 16384);
    PH_SYNC_IN();
    mfma_quad<4, 2>(acc, fa1, fb1);
    PH_SYNC_OUT();

    // phi4: stage B(t+2)h0 -> buf0; counted vmcnt (tile t+1 complete)
    stage2(gB + o2, lB);
    asm volatile("s_waitcnt vmcnt(6)" ::: "memory");
    __builtin_amdgcn_s_barrier();
    __builtin_amdgcn_sched_barrier(0);
    __builtin_amdgcn_s_setprio(1);
    mfma_quad<0, 2>(acc, fa0, fb1);
    PH_SYNC_OUT();

    // phi5: read buf1 fa0+fb0; stage B(t+2)h1 -> buf0
    rd_a(fa0, fA + 65536, s0, s1);
    rd_b(fb0, fB + 65536, s0, s1);
    stage2(gB + (size_t)128 * K2B + o2, lB + 16384);
    PH_SYNC_IN();
    mfma_quad<0, 0>(acc, fa0, fb0);
    PH_SYNC_OUT();

    // phi6: read buf1 fa1; stage A(t+3)h0 -> buf1
    rd_a(fa1, fA + 65536 + 16384, s0, s1);
    stage2(gA + o3, lA + 65536);
    PH_SYNC_IN();
    mfma_quad<4, 0>(acc, fa1, fb0);
    PH_SYNC_OUT();

    // phi7: read buf1 fb1; stage A(t+3)h1 -> buf1
    rd_b(fb1, fB + 65536 + 16384, s0, s1);
    stage2(gA + (size_t)128 * K2B + o3, lA + 65536 + 16384);
    PH_SYNC_IN();
    mfma_quad<4, 2>(acc, fa1, fb1);
    PH_SYNC_OUT();

    // phi8: stage B(t+3)h0 -> buf1; counted vmcnt (tile t+2 complete)
    stage2(gB + o3, lB + 65536);
    asm volatile("s_waitcnt vmcnt(6)" ::: "memory");
    __builtin_amdgcn_s_barrier();
    __builtin_amdgcn_sched_barrier(0);
    __builtin_amdgcn_s_setprio(1);
    mfma_quad<0, 2>(acc, fa0, fb1);
    PH_SYNC_OUT();
  }

  // drain in-flight gload_lds before LDS dealloc at wave exit
  asm volatile("s_waitcnt vmcnt(0)" ::: "memory");

  // epilogue: C/D layout col=lane&15 (n), row=quad*4+r (m)
#pragma unroll
  for (int an = 0; an < 4; ++an) {
    const int n = n0 + (an >> 1) * 128 + wn * 32 + (an & 1) * 16 + l16;
    const float bv = bias[n];
#pragma unroll
    for (int am = 0; am < 8; ++am) {
      const int m = m0 + (am >> 2) * 128 + wm * 64 + (am & 3) * 16 + quad * 4;
#pragma unroll
      for (int r = 0; r < 4; ++r)
        C[(size_t)(m + r) * N_DIM + n] = acc[am][an][r] + bv;
    }
  }
}

// ---------------------------------------------------------------------------
// Fallback: old 128x128 m97-structure GEMM, AMODE 1 (A fp32 fused cvt).
// ---------------------------------------------------------------------------
template <int AMODE>
__launch_bounds__(256)
__global__ void qgemm(const __bf16* __restrict__ Ab, const float* __restrict__ Af,
                      const __bf16* __restrict__ Bw, const float* __restrict__ bias,
                      float* __restrict__ C) {
  __shared__ __bf16 As[BM * BK];
  __shared__ __bf16 Bs[BN * BK];

  const int tid = threadIdx.x;
  const int wave = tid >> 6;
  const int lane = tid & 63;
  const int l16 = lane & 15;
  const int quad = lane >> 4;
  const int wm = wave >> 1;
  const int wn = wave & 1;
  const int n0 = blockIdx.x * BN;
  const int m0 = blockIdx.y * BM;

  f32x4_t acc[4][4];
#pragma unroll
  for (int i = 0; i < 4; ++i)
#pragma unroll
    for (int j = 0; j < 4; ++j) acc[i][j] = (f32x4_t){0.f, 0.f, 0.f, 0.f};

  const int skq = lane & 3;
  const __bf16* gB0 =
      Bw + (size_t)(n0 + wave * 32 + (lane >> 2)) * K_DIM + skq * 8;
  __bf16* lB0 = Bs + (wave * 32) * BK;

  const __bf16* gA0 =
      (AMODE == 0) ? Ab + (size_t)(m0 + wave * 32 + (lane >> 2)) * K_DIM + skq * 8
                   : nullptr;
  __bf16* lA0 = As + (wave * 32) * BK;

  const int ar = tid >> 2;
  const int akq = tid & 3;
  const float* gX0 =
      (AMODE == 1) ? Af + (size_t)(m0 + ar) * K_DIM + akq * 8 : nullptr;
  __bf16* lAf = As + ar * BK + akq * 8;

  for (int kt = 0; kt < K_DIM; kt += BK) {
    __syncthreads();
    GLD_LDS16(gB0 + kt, lB0);
    GLD_LDS16(gB0 + kt + (size_t)16 * K_DIM, lB0 + 16 * BK);
    if (AMODE == 0) {
      GLD_LDS16(gA0 + kt, lA0);
      GLD_LDS16(gA0 + kt + (size_t)16 * K_DIM, lA0 + 16 * BK);
    } else {
#pragma unroll
      for (int p = 0; p < 2; ++p) {
        const float4* s = (const float4*)(gX0 + (size_t)p * 64 * K_DIM + kt);
        const float4 f0 = s[0], f1 = s[1];
        bf16x8_t v;
        v[0] = (__bf16)f0.x; v[1] = (__bf16)f0.y;
        v[2] = (__bf16)f0.z; v[3] = (__bf16)f0.w;
        v[4] = (__bf16)f1.x; v[5] = (__bf16)f1.y;
        v[6] = (__bf16)f1.z; v[7] = (__bf16)f1.w;
        *(bf16x8_t*)(lAf + p * 64 * BK) = v;
      }
    }
    __syncthreads();

    bf16x8_t fa[4], fb[4];
#pragma unroll
    for (int t = 0; t < 4; ++t)
      fa[t] = *(const bf16x8_t*)(As + (wm * 64 + t * 16 + l16) * BK + quad * 8);
#pragma unroll
    for (int t = 0; t < 4; ++t)
      fb[t] = *(const bf16x8_t*)(Bs + (wn * 64 + t * 16 + l16) * BK + quad * 8);
#pragma unroll
    for (int i = 0; i < 4; ++i)
#pragma unroll
      for (int j = 0; j < 4; ++j)
        acc[i][j] =
            __builtin_amdgcn_mfma_f32_16x16x32_bf16(fa[i], fb[j], acc[i][j], 0, 0, 0);
  }

#pragma unroll
  for (int j = 0; j < 4; ++j) {
    const int n = n0 + wn * 64 + j * 16 + l16;
    const float bv = bias[n];
#pragma unroll
    for (int i = 0; i < 4; ++i) {
      const int mb = m0 + wm * 64 + i * 16 + quad * 4;
#pragma unroll
      for (int r = 0; r < 4; ++r)
        C[(size_t)(mb + r) * N_DIM + n] = acc[i][j][r] + bv;
    }
  }
}

// ---------------------------------------------------------------------------
// Safety-net: naive fp32 kernel (no workspace needed).
// ---------------------------------------------------------------------------
__global__ void qgemm_naive(const float* __restrict__ X, const int* __restrict__ WP,
                            const float* __restrict__ S, const float* __restrict__ BG,
                            const float* __restrict__ bias, float* __restrict__ C) {
  const int n = blockIdx.x * 256 + threadIdx.x;
  const int m = blockIdx.y;
  const float* x = X + (size_t)m * K_DIM;
  float acc = 0.f;
  for (int g = 0; g < 32; ++g) {
    const float s = S[n * 32 + g];
    const float b = BG[n * 32 + g];
    for (int wd = 0; wd < 16; ++wd) {
      const unsigned w = (unsigned)WP[n * 512 + g * 16 + wd];
      const int kb = g * 128 + wd * 8;
#pragma unroll
      for (int i = 0; i < 8; ++i)
        acc += (s * (float)((w >> (4 * i)) & 15u) + b) * x[kb + i];
    }
  }
  C[(size_t)m * N_DIM + n] = acc + bias[n];
}

extern "C" void kernel_launch(void* const* d_in, const int* in_sizes, int n_in,
                              void* d_out, int out_size, void* d_ws, size_t ws_size,
                              hipStream_t stream) {
  const float* X = (const float*)d_in[0];
  const int* WP = (const int*)d_in[1];
  const float* S = (const float*)d_in[2];
  const float* BG = (const float*)d_in[3];
  const float* BIAS = (const float*)d_in[4];
  float* C = (float*)d_out;

  const size_t needW = (size_t)N_DIM * K_DIM * 2;  // 90,177,536 B
  const size_t needX = (size_t)M_DIM * K_DIM * 2;  // 67,108,864 B

  if (ws_size >= needW + needX) {
    __bf16* W = (__bf16*)d_ws;
    __bf16* Xb = (__bf16*)((char*)d_ws + needW);
    dequant_w<<<(N_DIM * 512) / 256, 256, 0, stream>>>(WP, S, BG, W);
    cvt_x<<<(M_DIM * K_DIM) / (256 * 8), 256, 0, stream>>>(X, Xb);
    qgemm8<<<dim3((N_DIM / 256) * (M_DIM / 256)), 512, 0, stream>>>(Xb, W, BIAS, C);
  } else if (ws_size >= needW) {
    __bf16* W = (__bf16*)d_ws;
    dequant_w<<<(N_DIM * 512) / 256, 256, 0, stream>>>(WP, S, BG, W);
    qgemm<1><<<dim3(N_DIM / BN, M_DIM / BM), 256, 0, stream>>>(nullptr, X, W, BIAS, C);
  } else {
    qgemm_naive<<<dim3(N_DIM / 256, M_DIM), 256, 0, stream>>>(X, WP, S, BG, BIAS, C);
  }
}

// Round 3
// 1058.347 us; speedup vs baseline: 1.4899x; 1.0058x over previous
//
#include <hip/hip_runtime.h>

#define K_DIM 4096
#define N_DIM 11008
#define M_DIM 8192
#define K2B (K_DIM * 2)  // bf16 row stride in bytes

// ---- old 128^2 kernel tile params (fallback path) ----
#define BM 128
#define BN 128
#define BK 32

typedef __bf16 bf16x8_t __attribute__((ext_vector_type(8)));
typedef float f32x4_t __attribute__((ext_vector_type(4)));

#define GLD_LDS16(g, l)                                                        \
  __builtin_amdgcn_global_load_lds(                                            \
      (const __attribute__((address_space(1))) void*)(g),                      \
      (__attribute__((address_space(3))) void*)(l), 16, 0, 0)

// ---------------------------------------------------------------------------
// Kernel 1: unpack int4 + dequant (s*q + b) -> bf16 W (N_DIM x K_DIM, K-contig)
// ---------------------------------------------------------------------------
__global__ void dequant_w(const int* __restrict__ wp, const float* __restrict__ sc,
                          const float* __restrict__ bg, __bf16* __restrict__ W) {
  const int tid = blockIdx.x * 256 + threadIdx.x;  // < 11008*512
  const unsigned w = (unsigned)wp[tid];
  const int row = tid >> 9;
  const int word = tid & 511;
  const int g = word >> 4;
  const float s = sc[row * 32 + g];
  const float b = bg[row * 32 + g];
  bf16x8_t v;
#pragma unroll
  for (int i = 0; i < 8; ++i)
    v[i] = (__bf16)(s * (float)((w >> (4 * i)) & 15u) + b);
  ((bf16x8_t*)W)[tid] = v;
}

// ---------------------------------------------------------------------------
// Kernel 2: x fp32 -> bf16 (8 elems/thread)
// ---------------------------------------------------------------------------
__global__ void cvt_x(const float* __restrict__ X, __bf16* __restrict__ Xb) {
  const size_t t = (size_t)blockIdx.x * 256 + threadIdx.x;
  const float4* s = ((const float4*)X) + 2 * t;
  const float4 f0 = s[0], f1 = s[1];
  bf16x8_t v;
  v[0] = (__bf16)f0.x; v[1] = (__bf16)f0.y; v[2] = (__bf16)f0.z; v[3] = (__bf16)f0.w;
  v[4] = (__bf16)f1.x; v[5] = (__bf16)f1.y; v[6] = (__bf16)f1.z; v[7] = (__bf16)f1.w;
  ((bf16x8_t*)Xb)[t] = v;
}

// ---------------------------------------------------------------------------
// Kernel 2b: init split-K tail tiles (1280..1375) of C with bias.
// Both half-K GEMM jobs then atomicAdd partials on top (stream-ordered).
// grid = 96 tiles * 256 rows = 24576 blocks x 256 thr (1 row-chunk each).
// ---------------------------------------------------------------------------
__global__ void init_ctail(const float* __restrict__ bias, float* __restrict__ C) {
  const int t = 1280 + (blockIdx.x >> 8);
  const int mi = blockIdx.x & 255;
  const int m0 = (t / 43) * 256;
  const int n0 = (t % 43) * 256;
  const int n = n0 + threadIdx.x;
  C[(size_t)(m0 + mi) * N_DIM + n] = bias[n];
}

// ---------------------------------------------------------------------------
// Kernel 3: 256x256x64 8-phase bf16 GEMM-BT (m201 template, T1+T2+T3/T4+T5).
// C[M,N] = A[M,K] * W[N,K]^T + bias.  512 thr = 8 waves (2M x 4N), each wave
// 128x64 via 8x4 acc of 16x16x32 MFMA.  LDS 128KB: buf{0,1} x (A 32K | B 32K).
// Tail balancing: 1280 full-K jobs (exactly 5 rounds of 256 CUs) + 192
// half-K jobs (tiles 1280..1375 split at K=2048) forming a half-length final
// round: utilization 89.6% -> 97.7%.  Half jobs atomicAdd onto bias-inited C.
// Per-XCD: 160 full + 24 half jobs, contiguous tile range (L2 locality).
// ---------------------------------------------------------------------------
__device__ __forceinline__ void stage2(const char* g, char* l) {
  GLD_LDS16(g, l);
  GLD_LDS16(g + (size_t)64 * K2B, l + 8192);
}

template <int AM, int AN>
__device__ __forceinline__ void mfma_quad(f32x4_t (&acc)[8][4],
                                          const bf16x8_t (&A)[4][2],
                                          const bf16x8_t (&B)[2][2]) {
#pragma unroll
  for (int mi = 0; mi < 4; ++mi)
#pragma unroll
    for (int nj = 0; nj < 2; ++nj)
#pragma unroll
      for (int ks = 0; ks < 2; ++ks)
        acc[AM + mi][AN + nj] = __builtin_amdgcn_mfma_f32_16x16x32_bf16(
            A[mi][ks], B[nj][ks], acc[AM + mi][AN + nj], 0, 0, 0);
}

__device__ __forceinline__ void rd_a(bf16x8_t (&d)[4][2], const char* p, int s0, int s1) {
#pragma unroll
  for (int mi = 0; mi < 4; ++mi) {
    d[mi][0] = *(const bf16x8_t*)(p + mi * 2048 + s0);
    d[mi][1] = *(const bf16x8_t*)(p + mi * 2048 + s1);
  }
}
__device__ __forceinline__ void rd_b(bf16x8_t (&d)[2][2], const char* p, int s0, int s1) {
#pragma unroll
  for (int nj = 0; nj < 2; ++nj) {
    d[nj][0] = *(const bf16x8_t*)(p + nj * 2048 + s0);
    d[nj][1] = *(const bf16x8_t*)(p + nj * 2048 + s1);
  }
}

#define PH_SYNC_IN()                                                           \
  do {                                                                         \
    __builtin_amdgcn_s_barrier();                                              \
    asm volatile("s_waitcnt lgkmcnt(0)" ::: "memory");                         \
    __builtin_amdgcn_sched_barrier(0);                                         \
    __builtin_amdgcn_s_setprio(1);                                             \
  } while (0)
#define PH_SYNC_OUT()                                                          \
  do {                                                                         \
    __builtin_amdgcn_s_setprio(0);                                             \
    __builtin_amdgcn_sched_barrier(0);                                         \
    __builtin_amdgcn_s_barrier();                                              \
  } while (0)

__launch_bounds__(512, 2)
__global__ void qgemm8(const __bf16* __restrict__ Ab, const __bf16* __restrict__ Bw,
                       const float* __restrict__ bias, float* __restrict__ C) {
  __shared__ alignas(128) char smem[131072];
  const int tid = threadIdx.x;
  const int lane = tid & 63;
  const int wave = tid >> 6;
  const int wm = wave >> 2;  // 0..1
  const int wn = wave & 3;   // 0..3
  const int l16 = lane & 15;
  const int quad = lane >> 4;

  // job mapping: gid -> (XCD x, local l).  l<160: full-K tile x*160+l.
  // l>=160: half-K job h = x*24+(l-160) -> tile 1280+h/2, K-half h&1.
  const int gid = (int)blockIdx.x;  // 0..1471
  const int x = gid & 7;
  const int l = gid >> 3;  // 0..183
  int tile, kh, nit;
  if (l < 160) {
    tile = x * 160 + l;
    kh = 0;
    nit = 32;
  } else {
    const int h = x * 24 + (l - 160);
    tile = 1280 + (h >> 1);
    kh = h & 1;
    nit = 16;
  }
  const int m0 = (tile / 43) * 256;
  const int n0 = (tile % 43) * 256;
  const size_t kbase = (size_t)kh * 4096;  // byte offset into K (2048 bf16)

  // staging source (per-lane, pre-swizzled: phys slot L&7 holds logical slot
  // (L&7)^(row&7); row&7 == (tid>>3)&7 for every staged octet)
  const int rr = tid >> 3;  // 0..63
  const int sw = ((tid & 7) ^ (rr & 7)) * 16;
  const char* gA = (const char*)Ab + (size_t)(m0 + rr) * K2B + sw + kbase;
  const char* gB = (const char*)Bw + (size_t)(n0 + rr) * K2B + sw + kbase;
  // staging LDS dest (wave-uniform base; HW adds lane*16)
  char* lA = smem + wave * 1024;
  char* lB = smem + 32768 + wave * 1024;

  // fragment ds_read: logical slot s=ks*4+quad at phys byte ((s^(row&7))*16)
  const int s0 = ((0 + quad) ^ (l16 & 7)) * 16;
  const int s1 = ((4 + quad) ^ (l16 & 7)) * 16;
  const char* fA = smem + (wm * 64 + l16) * 128;
  const char* fB = smem + 32768 + (wn * 32 + l16) * 128;

  f32x4_t acc[8][4];
#pragma unroll
  for (int i = 0; i < 8; ++i)
#pragma unroll
    for (int j = 0; j < 4; ++j) acc[i][j] = (f32x4_t){0.f, 0.f, 0.f, 0.f};

  // prologue: tile0 all 4 halves -> buf0, tile1 Ah0/Ah1/Bh0 -> buf1 (14 loads)
  stage2(gA, lA);
  stage2(gA + (size_t)128 * K2B, lA + 16384);
  stage2(gB, lB);
  stage2(gB + (size_t)128 * K2B, lB + 16384);
  stage2(gA + 128, lA + 65536);
  stage2(gA + (size_t)128 * K2B + 128, lA + 65536 + 16384);
  stage2(gB + 128, lB + 65536);
  asm volatile("s_waitcnt vmcnt(6)" ::: "memory");  // tile0 complete
  __builtin_amdgcn_s_barrier();

  bf16x8_t fa0[4][2], fa1[4][2], fb0[2][2], fb1[2][2];
  const int kmaxt = 2 * nit - 1;  // last valid K-tile index (clamp target)

#pragma unroll 1
  for (int it = 0; it < nit; ++it) {
    const size_t o1 = (size_t)(2 * it + 1) * 128;
    const int tt2 = 2 * it + 2, tt3 = 2 * it + 3;
    const size_t o2 = (size_t)(tt2 < kmaxt ? tt2 : kmaxt) * 128;  // clamp: dead
    const size_t o3 = (size_t)(tt3 < kmaxt ? tt3 : kmaxt) * 128;

    // phi1: read buf0 fa0+fb0 (12 ds_read); stage B(t+1)h1 -> buf1
    rd_a(fa0, fA, s0, s1);
    rd_b(fb0, fB, s0, s1);
    stage2(gB + (size_t)128 * K2B + o1, lB + 65536 + 16384);
    PH_SYNC_IN();
    mfma_quad<0, 0>(acc, fa0, fb0);
    PH_SYNC_OUT();

    // phi2: read buf0 fa1; stage A(t+2)h0 -> buf0 (region dead since phi1)
    rd_a(fa1, fA + 16384, s0, s1);
    stage2(gA + o2, lA);
    PH_SYNC_IN();
    mfma_quad<4, 0>(acc, fa1, fb0);
    PH_SYNC_OUT();

    // phi3: read buf0 fb1; stage A(t+2)h1 -> buf0
    rd_b(fb1, fB + 16384, s0, s1);
    stage2(gA + (size_t)128 * K2B + o2, lA + 16384);
    PH_SYNC_IN();
    mfma_quad<4, 2>(acc, fa1, fb1);
    PH_SYNC_OUT();

    // phi4: stage B(t+2)h0 -> buf0; counted vmcnt (tile t+1 complete)
    stage2(gB + o2, lB);
    asm volatile("s_waitcnt vmcnt(6)" ::: "memory");
    __builtin_amdgcn_s_barrier();
    __builtin_amdgcn_sched_barrier(0);
    __builtin_amdgcn_s_setprio(1);
    mfma_quad<0, 2>(acc, fa0, fb1);
    PH_SYNC_OUT();

    // phi5: read buf1 fa0+fb0; stage B(t+2)h1 -> buf0
    rd_a(fa0, fA + 65536, s0, s1);
    rd_b(fb0, fB + 65536, s0, s1);
    stage2(gB + (size_t)128 * K2B + o2, lB + 16384);
    PH_SYNC_IN();
    mfma_quad<0, 0>(acc, fa0, fb0);
    PH_SYNC_OUT();

    // phi6: read buf1 fa1; stage A(t+3)h0 -> buf1
    rd_a(fa1, fA + 65536 + 16384, s0, s1);
    stage2(gA + o3, lA + 65536);
    PH_SYNC_IN();
    mfma_quad<4, 0>(acc, fa1, fb0);
    PH_SYNC_OUT();

    // phi7: read buf1 fb1; stage A(t+3)h1 -> buf1
    rd_b(fb1, fB + 65536 + 16384, s0, s1);
    stage2(gA + (size_t)128 * K2B + o3, lA + 65536 + 16384);
    PH_SYNC_IN();
    mfma_quad<4, 2>(acc, fa1, fb1);
    PH_SYNC_OUT();

    // phi8: stage B(t+3)h0 -> buf1; counted vmcnt (tile t+2 complete)
    stage2(gB + o3, lB + 65536);
    asm volatile("s_waitcnt vmcnt(6)" ::: "memory");
    __builtin_amdgcn_s_barrier();
    __builtin_amdgcn_sched_barrier(0);
    __builtin_amdgcn_s_setprio(1);
    mfma_quad<0, 2>(acc, fa0, fb1);
    PH_SYNC_OUT();
  }

  // drain in-flight gload_lds before LDS dealloc at wave exit
  asm volatile("s_waitcnt vmcnt(0)" ::: "memory");

  // epilogue: C/D layout col=lane&15 (n), row=quad*4+r (m)
  if (nit == 32) {
#pragma unroll
    for (int an = 0; an < 4; ++an) {
      const int n = n0 + (an >> 1) * 128 + wn * 32 + (an & 1) * 16 + l16;
      const float bv = bias[n];
#pragma unroll
      for (int am = 0; am < 8; ++am) {
        const int m = m0 + (am >> 2) * 128 + wm * 64 + (am & 3) * 16 + quad * 4;
#pragma unroll
        for (int r = 0; r < 4; ++r)
          C[(size_t)(m + r) * N_DIM + n] = acc[am][an][r] + bv;
      }
    }
  } else {
    // half-K job: bias pre-written by init_ctail; add partial sums
#pragma unroll
    for (int an = 0; an < 4; ++an) {
      const int n = n0 + (an >> 1) * 128 + wn * 32 + (an & 1) * 16 + l16;
#pragma unroll
      for (int am = 0; am < 8; ++am) {
        const int m = m0 + (am >> 2) * 128 + wm * 64 + (am & 3) * 16 + quad * 4;
#pragma unroll
        for (int r = 0; r < 4; ++r)
          atomicAdd(&C[(size_t)(m + r) * N_DIM + n], acc[am][an][r]);
      }
    }
  }
}

// ---------------------------------------------------------------------------
// Fallback: old 128x128 m97-structure GEMM, AMODE 1 (A fp32 fused cvt).
// ---------------------------------------------------------------------------
template <int AMODE>
__launch_bounds__(256)
__global__ void qgemm(const __bf16* __restrict__ Ab, const float* __restrict__ Af,
                      const __bf16* __restrict__ Bw, const float* __restrict__ bias,
                      float* __restrict__ C) {
  __shared__ __bf16 As[BM * BK];
  __shared__ __bf16 Bs[BN * BK];

  const int tid = threadIdx.x;
  const int wave = tid >> 6;
  const int lane = tid & 63;
  const int l16 = lane & 15;
  const int quad = lane >> 4;
  const int wm = wave >> 1;
  const int wn = wave & 1;
  const int n0 = blockIdx.x * BN;
  const int m0 = blockIdx.y * BM;

  f32x4_t acc[4][4];
#pragma unroll
  for (int i = 0; i < 4; ++i)
#pragma unroll
    for (int j = 0; j < 4; ++j) acc[i][j] = (f32x4_t){0.f, 0.f, 0.f, 0.f};

  const int skq = lane & 3;
  const __bf16* gB0 =
      Bw + (size_t)(n0 + wave * 32 + (lane >> 2)) * K_DIM + skq * 8;
  __bf16* lB0 = Bs + (wave * 32) * BK;

  const __bf16* gA0 =
      (AMODE == 0) ? Ab + (size_t)(m0 + wave * 32 + (lane >> 2)) * K_DIM + skq * 8
                   : nullptr;
  __bf16* lA0 = As + (wave * 32) * BK;

  const int ar = tid >> 2;
  const int akq = tid & 3;
  const float* gX0 =
      (AMODE == 1) ? Af + (size_t)(m0 + ar) * K_DIM + akq * 8 : nullptr;
  __bf16* lAf = As + ar * BK + akq * 8;

  for (int kt = 0; kt < K_DIM; kt += BK) {
    __syncthreads();
    GLD_LDS16(gB0 + kt, lB0);
    GLD_LDS16(gB0 + kt + (size_t)16 * K_DIM, lB0 + 16 * BK);
    if (AMODE == 0) {
      GLD_LDS16(gA0 + kt, lA0);
      GLD_LDS16(gA0 + kt + (size_t)16 * K_DIM, lA0 + 16 * BK);
    } else {
#pragma unroll
      for (int p = 0; p < 2; ++p) {
        const float4* s = (const float4*)(gX0 + (size_t)p * 64 * K_DIM + kt);
        const float4 f0 = s[0], f1 = s[1];
        bf16x8_t v;
        v[0] = (__bf16)f0.x; v[1] = (__bf16)f0.y;
        v[2] = (__bf16)f0.z; v[3] = (__bf16)f0.w;
        v[4] = (__bf16)f1.x; v[5] = (__bf16)f1.y;
        v[6] = (__bf16)f1.z; v[7] = (__bf16)f1.w;
        *(bf16x8_t*)(lAf + p * 64 * BK) = v;
      }
    }
    __syncthreads();

    bf16x8_t fa[4], fb[4];
#pragma unroll
    for (int t = 0; t < 4; ++t)
      fa[t] = *(const bf16x8_t*)(As + (wm * 64 + t * 16 + l16) * BK + quad * 8);
#pragma unroll
    for (int t = 0; t < 4; ++t)
      fb[t] = *(const bf16x8_t*)(Bs + (wn * 64 + t * 16 + l16) * BK + quad * 8);
#pragma unroll
    for (int i = 0; i < 4; ++i)
#pragma unroll
      for (int j = 0; j < 4; ++j)
        acc[i][j] =
            __builtin_amdgcn_mfma_f32_16x16x32_bf16(fa[i], fb[j], acc[i][j], 0, 0, 0);
  }

#pragma unroll
  for (int j = 0; j < 4; ++j) {
    const int n = n0 + wn * 64 + j * 16 + l16;
    const float bv = bias[n];
#pragma unroll
    for (int i = 0; i < 4; ++i) {
      const int mb = m0 + wm * 64 + i * 16 + quad * 4;
#pragma unroll
      for (int r = 0; r < 4; ++r)
        C[(size_t)(mb + r) * N_DIM + n] = acc[i][j][r] + bv;
    }
  }
}

// ---------------------------------------------------------------------------
// Safety-net: naive fp32 kernel (no workspace needed).
// ---------------------------------------------------------------------------
__global__ void qgemm_naive(const float* __restrict__ X, const int* __restrict__ WP,
                            const float* __restrict__ S, const float* __restrict__ BG,
                            const float* __restrict__ bias, float* __restrict__ C) {
  const int n = blockIdx.x * 256 + threadIdx.x;
  const int m = blockIdx.y;
  const float* x = X + (size_t)m * K_DIM;
  float acc = 0.f;
  for (int g = 0; g < 32; ++g) {
    const float s = S[n * 32 + g];
    const float b = BG[n * 32 + g];
    for (int wd = 0; wd < 16; ++wd) {
      const unsigned w = (unsigned)WP[n * 512 + g * 16 + wd];
      const int kb = g * 128 + wd * 8;
#pragma unroll
      for (int i = 0; i < 8; ++i)
        acc += (s * (float)((w >> (4 * i)) & 15u) + b) * x[kb + i];
    }
  }
  C[(size_t)m * N_DIM + n] = acc + bias[n];
}

extern "C" void kernel_launch(void* const* d_in, const int* in_sizes, int n_in,
                              void* d_out, int out_size, void* d_ws, size_t ws_size,
                              hipStream_t stream) {
  const float* X = (const float*)d_in[0];
  const int* WP = (const int*)d_in[1];
  const float* S = (const float*)d_in[2];
  const float* BG = (const float*)d_in[3];
  const float* BIAS = (const float*)d_in[4];
  float* C = (float*)d_out;

  const size_t needW = (size_t)N_DIM * K_DIM * 2;  // 90,177,536 B
  const size_t needX = (size_t)M_DIM * K_DIM * 2;  // 67,108,864 B

  if (ws_size >= needW + needX) {
    __bf16* W = (__bf16*)d_ws;
    __bf16* Xb = (__bf16*)((char*)d_ws + needW);
    dequant_w<<<(N_DIM * 512) / 256, 256, 0, stream>>>(WP, S, BG, W);
    cvt_x<<<(M_DIM * K_DIM) / (256 * 8), 256, 0, stream>>>(X, Xb);
    init_ctail<<<96 * 256, 256, 0, stream>>>(BIAS, C);
    // 1280 full-K jobs + 192 half-K jobs = 1472 blocks
    qgemm8<<<dim3(1472), 512, 0, stream>>>(Xb, W, BIAS, C);
  } else if (ws_size >= needW) {
    __bf16* W = (__bf16*)d_ws;
    dequant_w<<<(N_DIM * 512) / 256, 256, 0, stream>>>(WP, S, BG, W);
    qgemm<1><<<dim3(N_DIM / BN, M_DIM / BM), 256, 0, stream>>>(nullptr, X, W, BIAS, C);
  } else {
    qgemm_naive<<<dim3(N_DIM / 256, M_DIM), 256, 0, stream>>>(X, WP, S, BG, BIAS, C);
  }
}